// Round 6
// baseline (38002.493 us; speedup 1.0000x reference)
//
#include <hip/hip_runtime.h>
#include <cmath>

// Problem dims (fixed by reference)
#define B_   128
#define T_   500
#define MEL_ 80
#define RED_ 2
#define D_   256   // decoder dim
#define E_   128   // encoder/prenet-out dim
#define PRE_ 256   // prenet hidden
#define L_   256   // encoder length
#define TPB  1024
#define ENC_C 256  // ushorts per enc row (512B exactly; XOR-swizzled 16B chunks)
#define PTT  10    // timesteps per pre-pass block (500 % 10 == 0)

__device__ __forceinline__ float sigmoidf_(float x) { return 1.f / (1.f + expf(-x)); }
__device__ __forceinline__ float bflo(unsigned u) { return __uint_as_float(u << 16); }
__device__ __forceinline__ float bfhi(unsigned u) { return __uint_as_float(u & 0xFFFF0000u); }
__device__ __forceinline__ float bfval(ushort v) { return __uint_as_float(((unsigned)v) << 16); }
__device__ __forceinline__ ushort f2bf(float f) {
    unsigned u = __float_as_uint(f);
    return (ushort)((u + 0x7FFFu + ((u >> 16) & 1u)) >> 16);
}

__device__ __forceinline__ unsigned ld_acq(const unsigned* p) {
    return __hip_atomic_load(p, __ATOMIC_ACQUIRE, __HIP_MEMORY_SCOPE_AGENT);
}
__device__ __forceinline__ void st_rel(unsigned* p, unsigned v) {
    __hip_atomic_store(p, v, __ATOMIC_RELEASE, __HIP_MEMORY_SCOPE_AGENT);
}

// accumulate 8 bf16 (one uint4) against 8 fp32
__device__ __forceinline__ float acc8(uint4 u, const float* vv, float s) {
    s = fmaf(bflo(u.x), vv[0], s);
    s = fmaf(bfhi(u.x), vv[1], s);
    s = fmaf(bflo(u.y), vv[2], s);
    s = fmaf(bfhi(u.y), vv[3], s);
    s = fmaf(bflo(u.z), vv[4], s);
    s = fmaf(bfhi(u.z), vv[5], s);
    s = fmaf(bflo(u.w), vv[6], s);
    s = fmaf(bfhi(u.w), vv[7], s);
    return s;
}

// Wave-group-sequential packed bf16 weights: group g (64 tasks) stores chunks
// contiguously at uint4 index (g*CH + c)*64 + lane. Every wave load is 1KB
// fully contiguous. 4 accumulators, unroll 2 -> no spill at 64 VGPR.
template<int CH>
__device__ __forceinline__ float dotpk(const ushort* __restrict__ wp, int t, const float* v) {
    const uint4* w = reinterpret_cast<const uint4*>(wp) + (t >> 6) * (CH * 64) + (t & 63);
    float s0 = 0.f, s1 = 0.f, s2 = 0.f, s3 = 0.f;
#pragma unroll 2
    for (int c = 0; c < (CH & ~3); c += 4) {
        uint4 u0 = w[(c + 0) * 64];
        uint4 u1 = w[(c + 1) * 64];
        uint4 u2 = w[(c + 2) * 64];
        uint4 u3 = w[(c + 3) * 64];
        s0 = acc8(u0, v + (c + 0) * 8, s0);
        s1 = acc8(u1, v + (c + 1) * 8, s1);
        s2 = acc8(u2, v + (c + 2) * 8, s2);
        s3 = acc8(u3, v + (c + 3) * 8, s3);
    }
    if (CH & 2) {
        constexpr int c0 = CH & ~3;
        uint4 u0 = w[(c0 + 0) * 64];
        uint4 u1 = w[(c0 + 1) * 64];
        s0 = acc8(u0, v + (c0 + 0) * 8, s0);
        s1 = acc8(u1, v + (c0 + 1) * 8, s1);
    }
    return (s0 + s1) + (s2 + s3);
}

// fp32 source -> bf16 wave-group-sequential packed layout
__global__ void pack_bf16_kernel(const float* __restrict__ src,
                                 ushort* __restrict__ dst,
                                 int NT, int CH, int dA, int mA, int mB) {
    int i = blockIdx.x * blockDim.x + threadIdx.x;
    int n = NT * CH * 8;
    if (i >= n) return;
    int i4 = i >> 3, e = i & 7;
    int lane = i4 & 63;
    int q = i4 >> 6;
    int c = q % CH;
    int g = q / CH;
    int t = g * 64 + lane;
    dst[i] = f2bf(src[(t / dA) * mA + (t % dA) * mB + c * 8 + e]);
}

__global__ void init_flags_kernel(unsigned* __restrict__ f, int n) {
    int i = blockIdx.x * blockDim.x + threadIdx.x;
    if (i < n) f[i] = 0u;
}

// -------- Pre-pass: prenet + attention-GRU input gates (verified r3/r4) -----
__global__ __launch_bounds__(256) void prenet_gi_kernel(
    const float* __restrict__ dec_input,
    const float* __restrict__ pre_w1, const float* __restrict__ pre_b1,
    const float* __restrict__ pre_w2, const float* __restrict__ pre_b2,
    const float* __restrict__ attn_wih, const float* __restrict__ attn_bih,
    ushort* __restrict__ gi_out,   // chunk-local [nb, T, 3*D] bf16
    int b0)
{
    const int blk = blockIdx.x;
    const int bl  = blk / (T_ / PTT);
    const int b   = b0 + bl;
    const int t0  = (blk % (T_ / PTT)) * PTT;
    const int tid = threadIdx.x;

    __shared__ float fr[PTT][MEL_];
    __shared__ float x1[PTT][PRE_];
    __shared__ float x2[PTT][E_];

    for (int i = tid; i < PTT * MEL_; i += 256) {
        int f = i / MEL_, m = i - f * MEL_;
        fr[f][m] = dec_input[((size_t)b * T_ + t0 + f) * MEL_ + m];
    }
    __syncthreads();

    {
        float acc[PTT];
#pragma unroll
        for (int f = 0; f < PTT; ++f) acc[f] = pre_b1[tid];
        const float4* wr = reinterpret_cast<const float4*>(pre_w1 + tid * MEL_);
        for (int k4 = 0; k4 < MEL_ / 4; ++k4) {
            float4 w = wr[k4];
#pragma unroll
            for (int f = 0; f < PTT; ++f) {
                const float* fp = &fr[f][k4 * 4];
                acc[f] = fmaf(w.x, fp[0], fmaf(w.y, fp[1], fmaf(w.z, fp[2], fmaf(w.w, fp[3], acc[f]))));
            }
        }
#pragma unroll
        for (int f = 0; f < PTT; ++f) x1[f][tid] = fmaxf(acc[f], 0.f);
    }
    __syncthreads();

    if (tid < E_) {
        float acc[PTT];
#pragma unroll
        for (int f = 0; f < PTT; ++f) acc[f] = pre_b2[tid];
        const float4* wr = reinterpret_cast<const float4*>(pre_w2 + tid * PRE_);
        for (int k4 = 0; k4 < PRE_ / 4; ++k4) {
            float4 w = wr[k4];
#pragma unroll
            for (int f = 0; f < PTT; ++f) {
                const float* fp = &x1[f][k4 * 4];
                acc[f] = fmaf(w.x, fp[0], fmaf(w.y, fp[1], fmaf(w.z, fp[2], fmaf(w.w, fp[3], acc[f]))));
            }
        }
#pragma unroll
        for (int f = 0; f < PTT; ++f) x2[f][tid] = fmaxf(acc[f], 0.f);
    }
    __syncthreads();

    for (int r = tid; r < 3 * D_; r += 256) {
        float acc[PTT];
#pragma unroll
        for (int f = 0; f < PTT; ++f) acc[f] = attn_bih[r];
        const float4* wr = reinterpret_cast<const float4*>(attn_wih + r * E_);
        for (int k4 = 0; k4 < E_ / 4; ++k4) {
            float4 w = wr[k4];
#pragma unroll
            for (int f = 0; f < PTT; ++f) {
                const float* fp = &x2[f][k4 * 4];
                acc[f] = fmaf(w.x, fp[0], fmaf(w.y, fp[1], fmaf(w.z, fp[2], fmaf(w.w, fp[3], acc[f]))));
            }
        }
#pragma unroll
        for (int f = 0; f < PTT; ++f)
            gi_out[((size_t)bl * T_ + t0 + f) * (3 * D_) + r] = f2bf(acc[f]);
    }
}

// Two-stage pipelined decoder, deadlock-free by construction:
//  - roles assigned by start-order TICKET (first nb starters = producers), so
//    a waiter only ever waits on an earlier-started block;
//  - the s_dec ring is FULL DEPTH (all T steps) -> producers never wait, run
//    to completion unconditionally; even fully serialized execution finishes.
// Producer: attn-gh/combine/scores/softmax/ctx/proj1 -> ring + flag(t+1).
// Consumer: merged rnn-gh (overlaps wait) -> wait -> rnn1 -> rnn2 -> proj2.
__global__ __launch_bounds__(TPB, 4) void decoder_pipe(
    const float* __restrict__ enc_output,  // [B,L,D] fp32
    const ushort* __restrict__ attn_whh, const float* __restrict__ attn_bhh,
    const ushort* __restrict__ proj1_w, const float* __restrict__ proj1_b,
    const ushort* __restrict__ rnn1_wih, const ushort* __restrict__ rnn1_whh,
    const float* __restrict__ rnn1_bih, const float* __restrict__ rnn1_bhh,
    const ushort* __restrict__ rnn2_wih, const ushort* __restrict__ rnn2_whh,
    const float* __restrict__ rnn2_bih, const float* __restrict__ rnn2_bhh,
    const ushort* __restrict__ proj2_w, const float* __restrict__ proj2_b,
    const ushort* __restrict__ gi_g,       // chunk-local [nb,T,3*D] bf16
    int b0, int nb,
    unsigned* __restrict__ flags,          // [nb] step flags + [nb] ticket ctr
    float* __restrict__ rdec,              // chunk-local [nb, T, D] fp32
    float* __restrict__ mel_out,   // [B, T*RED, MEL]
    float* __restrict__ align_out) // [B, L, T]
{
    const int tid  = threadIdx.x;
    const int lane = tid & 63;
    const int wv   = tid >> 6;

    // LDS (union of both roles) ~157.7 KB -> 1 block/CU
    __shared__ __align__(16) ushort s_enc[L_ * ENC_C];   // producer only
    __shared__ __align__(16) float P[3072];
    __shared__ __align__(16) float Pw[1536];
    __shared__ __align__(16) float s_ha[D_];
    __shared__ __align__(16) float s_h1[D_];
    __shared__ __align__(16) float s_h2[D_];
    __shared__ __align__(16) float s_dec[D_];
    __shared__ __align__(16) float s_y1[D_];
    __shared__ __align__(16) float s_y2[D_];
    __shared__ __align__(16) float s_ctx[D_];
    __shared__ __align__(16) float s_al[L_];
    __shared__ float s_pmax[4];
    __shared__ float s_psum[4];
    __shared__ unsigned s_ticket;

    // start-order role ticket
    if (tid == 0)
        s_ticket = __hip_atomic_fetch_add(flags + nb, 1u,
                                          __ATOMIC_RELAXED, __HIP_MEMORY_SCOPE_AGENT);
    __syncthreads();
    const unsigned tk = s_ticket;
    const bool isC = (tk >= (unsigned)nb);
    const int  bl  = isC ? (int)(tk - (unsigned)nb) : (int)tk;
    const int  b   = b0 + bl;

    unsigned* cpf = flags + bl;
    float* ringb = rdec + (size_t)bl * T_ * D_;

    if (!isC) {
        // ================= producer: attention front-end =================
        // stage enc[b] fp32 -> bf16 LDS, XOR-swizzled 16B chunks:
        // chunk c of row r stored at slot (c&24) | ((c&7)^(r&7))
        {
            const float4* eb = reinterpret_cast<const float4*>(enc_output + (size_t)b * L_ * D_);
            for (int i = tid; i < (L_ * D_) / 4; i += TPB) {
                float4 f = eb[i];
                int row = i >> 6;
                int c4  = i & 63;
                int c    = c4 >> 1;
                int half = c4 & 1;
                int slot = (c & 24) | ((c & 7) ^ (row & 7));
                uint2 pk;
                pk.x = (unsigned)f2bf(f.x) | ((unsigned)f2bf(f.y) << 16);
                pk.y = (unsigned)f2bf(f.z) | ((unsigned)f2bf(f.w) << 16);
                *reinterpret_cast<uint2*>(s_enc + row * ENC_C + slot * 8 + half * 4) = pk;
            }
        }
        if (tid < D_) s_ha[tid] = 0.f;
        __syncthreads();

        for (int t = 0; t < T_; ++t) {
            // [A] attn gh: 1536 half-dots (K=128) over whh with prev s_ha
            for (int task = tid; task < 1536; task += TPB)
                P[task] = dotpk<16>(attn_whh, task, s_ha + (task & 1) * 128);
            __syncthreads();

            // [B] attn GRU combine (gi from pre-pass)
            if (tid < D_) {
                const ushort* gp = gi_g + ((size_t)bl * T_ + t) * (3 * D_);
                float gir = bfval(gp[tid]);
                float giz = bfval(gp[D_ + tid]);
                float gin = bfval(gp[2 * D_ + tid]);
                float ghr = P[2 * tid] + P[2 * tid + 1] + attn_bhh[tid];
                float ghz = P[2 * (D_ + tid)] + P[2 * (D_ + tid) + 1] + attn_bhh[D_ + tid];
                float ghn = P[2 * (2 * D_ + tid)] + P[2 * (2 * D_ + tid) + 1] + attn_bhh[2 * D_ + tid];
                float r = sigmoidf_(gir + ghr);
                float z = sigmoidf_(giz + ghz);
                float n = tanhf(gin + r * ghn);
                s_ha[tid] = (1.f - z) * n + z * s_ha[tid];
            }
            __syncthreads();

            // [C] scores: 256 rows x 4-way K-split; swizzle-aware b128 reads
            {
                int p = tid >> 8, l = tid & 255;
                const uint4* rowp = reinterpret_cast<const uint4*>(s_enc + l * ENC_C) + p * 8;
                const float* v = s_ha + p * 64;
                int rot = l & 7;
                float a0 = 0.f, a1 = 0.f, a2 = 0.f, a3 = 0.f;
#pragma unroll
                for (int k = 0; k < 8; k += 4) {
                    uint4 u0 = rowp[(k + 0) ^ rot];
                    uint4 u1 = rowp[(k + 1) ^ rot];
                    uint4 u2 = rowp[(k + 2) ^ rot];
                    uint4 u3 = rowp[(k + 3) ^ rot];
                    a0 = acc8(u0, v + (k + 0) * 8, a0);
                    a1 = acc8(u1, v + (k + 1) * 8, a1);
                    a2 = acc8(u2, v + (k + 2) * 8, a2);
                    a3 = acc8(u3, v + (k + 3) * 8, a3);
                }
                P[p * 256 + l] = (a0 + a1) + (a2 + a3);
            }
            __syncthreads();
            float sc = 0.f, e = 0.f;
            // [D] finalize score + block max
            if (tid < L_) {
                sc = P[tid] + P[256 + tid] + P[512 + tid] + P[768 + tid];
                float m = sc;
                for (int o = 32; o > 0; o >>= 1) m = fmaxf(m, __shfl_xor(m, o, 64));
                if (lane == 0) s_pmax[wv] = m;
            }
            __syncthreads();
            // [E] exp + block sum
            if (tid < L_) {
                float mm = fmaxf(fmaxf(s_pmax[0], s_pmax[1]), fmaxf(s_pmax[2], s_pmax[3]));
                e = expf(sc - mm);
                float sm = e;
                for (int o = 32; o > 0; o >>= 1) sm += __shfl_xor(sm, o, 64);
                if (lane == 0) s_psum[wv] = sm;
            }
            __syncthreads();
            // [F] alignment
            if (tid < L_) {
                float denom = s_psum[0] + s_psum[1] + s_psum[2] + s_psum[3];
                float al = e / denom;
                s_al[tid] = al;
                align_out[((size_t)b * L_ + tid) * T_ + t] = al;
            }
            __syncthreads();

            // [G] ctx partials: 256 cols x 4-way L-split (swizzle-aware)
            {
                int p = tid >> 8, d = tid & 255;
                int chigh = (d >> 3) & 24, clow = (d >> 3) & 7, el = d & 7;
                const float* alp = s_al + p * 64;
                float a0 = 0.f, a1 = 0.f;
                for (int l8 = 0; l8 < 8; ++l8) {
                    const ushort* rb = s_enc + (p * 64 + l8 * 8) * ENC_C;
                    const float* al8 = alp + l8 * 8;
#pragma unroll
                    for (int dr = 0; dr < 8; ++dr) {
                        int slot = chigh | (clow ^ dr);
                        float vv = bfval(rb[dr * ENC_C + slot * 8 + el]);
                        if (dr & 1) a1 = fmaf(al8[dr], vv, a1);
                        else        a0 = fmaf(al8[dr], vv, a0);
                    }
                }
                P[p * 256 + d] = a0 + a1;
            }
            __syncthreads();
            // [H] ctx combine
            if (tid < D_)
                s_ctx[tid] = P[tid] + P[256 + tid] + P[512 + tid] + P[768 + tid];
            __syncthreads();

            // [I] proj1 partials: 256 rows, K=512 split 4-way; cat=[ctx,ha]
            {
                int p = tid >> 8;
                const float* v = (p < 2) ? (s_ctx + p * 128) : (s_ha + (p - 2) * 128);
                P[tid] = dotpk<16>(proj1_w, tid, v);
            }
            __syncthreads();
            // [J] proj1 combine -> ring (full depth; no waiting ever)
            if (tid < D_) {
                float v = P[tid] + P[256 + tid] + P[512 + tid] + P[768 + tid] + proj1_b[tid];
                ringb[(size_t)t * D_ + tid] = v;
            }
            __threadfence();
            __syncthreads();
            if (tid == 0) st_rel(cpf, (unsigned)(t + 1));
            // no extra barrier needed: next [A] writes P, which [J] already read;
            // the syncthreads above orders it.
        }
    } else {
        // ================= consumer: decoder back-end =================
        if (tid < D_) { s_h1[tid] = 0.f; s_h2[tid] = 0.f; }
        __syncthreads();

        for (int t = 0; t < T_; ++t) {
            // [P1] merged rnn gh (prev-step local state) — overlaps producer
            for (int task = tid; task < 3072; task += TPB) {
                if (task < 1536) {
                    P[task] = dotpk<16>(rnn1_whh, task, s_h1 + (task & 1) * 128);
                } else {
                    int u = task - 1536;
                    P[task] = dotpk<16>(rnn2_whh, u, s_h2 + (u & 1) * 128);
                }
            }
            // wait for s_dec(t); producer started earlier (ticket order) and
            // never waits, so this flag is guaranteed to arrive.
            if (tid == 0) {
                while (ld_acq(cpf) < (unsigned)(t + 1))
                    __builtin_amdgcn_s_sleep(8);
            }
            __syncthreads();
            // stage s_dec from ring (L1 freshly invalidated by the acquire)
            if (tid < D_) s_dec[tid] = ringb[(size_t)t * D_ + tid];
            __syncthreads();

            // [P2] rnn1 wih partials
            for (int task = tid; task < 1536; task += TPB)
                Pw[task] = dotpk<16>(rnn1_wih, task, s_dec + (task & 1) * 128);
            __syncthreads();
            // [P3] rnn1 combine
            if (tid < D_) {
                float gir = Pw[2 * tid] + Pw[2 * tid + 1] + rnn1_bih[tid];
                float giz = Pw[2 * (D_ + tid)] + Pw[2 * (D_ + tid) + 1] + rnn1_bih[D_ + tid];
                float gin = Pw[2 * (2 * D_ + tid)] + Pw[2 * (2 * D_ + tid) + 1] + rnn1_bih[2 * D_ + tid];
                float ghr = P[2 * tid] + P[2 * tid + 1] + rnn1_bhh[tid];
                float ghz = P[2 * (D_ + tid)] + P[2 * (D_ + tid) + 1] + rnn1_bhh[D_ + tid];
                float ghn = P[2 * (2 * D_ + tid)] + P[2 * (2 * D_ + tid) + 1] + rnn1_bhh[2 * D_ + tid];
                float r = sigmoidf_(gir + ghr);
                float z = sigmoidf_(giz + ghz);
                float n = tanhf(gin + r * ghn);
                float hn = (1.f - z) * n + z * s_h1[tid];
                s_h1[tid] = hn;
                s_y1[tid] = s_dec[tid] + hn;
            }
            __syncthreads();

            // [P4] rnn2 wih partials
            for (int task = tid; task < 1536; task += TPB)
                Pw[task] = dotpk<16>(rnn2_wih, task, s_y1 + (task & 1) * 128);
            __syncthreads();
            // [P5] rnn2 combine
            if (tid < D_) {
                float gir = Pw[2 * tid] + Pw[2 * tid + 1] + rnn2_bih[tid];
                float giz = Pw[2 * (D_ + tid)] + Pw[2 * (D_ + tid) + 1] + rnn2_bih[D_ + tid];
                float gin = Pw[2 * (2 * D_ + tid)] + Pw[2 * (2 * D_ + tid) + 1] + rnn2_bih[2 * D_ + tid];
                const float* gh = P + 1536;
                float ghr = gh[2 * tid] + gh[2 * tid + 1] + rnn2_bhh[tid];
                float ghz = gh[2 * (D_ + tid)] + gh[2 * (D_ + tid) + 1] + rnn2_bhh[D_ + tid];
                float ghn = gh[2 * (2 * D_ + tid)] + gh[2 * (2 * D_ + tid) + 1] + rnn2_bhh[2 * D_ + tid];
                float r = sigmoidf_(gir + ghr);
                float z = sigmoidf_(giz + ghz);
                float n = tanhf(gin + r * ghn);
                float hn = (1.f - z) * n + z * s_h2[tid];
                s_h2[tid] = hn;
                s_y2[tid] = s_y1[tid] + hn;
            }
            __syncthreads();

            // [P6] proj2 partials: 160 rows, K=256 split 4-way
            if (tid < 640)
                Pw[tid] = dotpk<8>(proj2_w, tid, s_y2 + (tid & 3) * 64);
            __syncthreads();
            // [P7] proj2 combine + mel store (no trailing barrier: next-iter
            // writes P after this read of Pw is ordered by the wait barriers)
            if (tid < MEL_ * RED_) {
                float s = Pw[4 * tid] + Pw[4 * tid + 1] + Pw[4 * tid + 2] + Pw[4 * tid + 3] + proj2_b[tid];
                mel_out[(size_t)b * (T_ * RED_ * MEL_) + (size_t)t * (MEL_ * RED_) + tid] = s;
            }
        }
    }
}

extern "C" void kernel_launch(void* const* d_in, const int* in_sizes, int n_in,
                              void* d_out, int out_size, void* d_ws, size_t ws_size,
                              hipStream_t stream) {
    const float* dec_input = (const float*)d_in[0];
    const float* enc_output= (const float*)d_in[1];
    const float* pre_w1    = (const float*)d_in[2];
    const float* pre_b1    = (const float*)d_in[3];
    const float* pre_w2    = (const float*)d_in[4];
    const float* pre_b2    = (const float*)d_in[5];
    const float* attn_wih  = (const float*)d_in[6];
    const float* attn_whh  = (const float*)d_in[7];
    const float* attn_bih  = (const float*)d_in[8];
    const float* attn_bhh  = (const float*)d_in[9];
    const float* proj1_w   = (const float*)d_in[10];
    const float* proj1_b   = (const float*)d_in[11];
    const float* rnn1_wih  = (const float*)d_in[12];
    const float* rnn1_whh  = (const float*)d_in[13];
    const float* rnn1_bih  = (const float*)d_in[14];
    const float* rnn1_bhh  = (const float*)d_in[15];
    const float* rnn2_wih  = (const float*)d_in[16];
    const float* rnn2_whh  = (const float*)d_in[17];
    const float* rnn2_bih  = (const float*)d_in[18];
    const float* rnn2_bhh  = (const float*)d_in[19];
    const float* proj2_w   = (const float*)d_in[20];
    const float* proj2_b   = (const float*)d_in[21];

    float* mel   = (float*)d_out;
    float* align = (float*)d_out + (size_t)B_ * T_ * RED_ * MEL_;

    // ---- workspace: [flags 4KB][packed ~2.31MB][ring nb*512000B][gi nb*768000B]
    unsigned* flags = (unsigned*)d_ws;
    size_t off = 4096;

    const int n_whh   = 3 * D_ * D_;        // 196608
    const int n_proj1 = D_ * 2 * D_;        // 131072
    const int n_proj2 = MEL_ * RED_ * D_;   // 40960

    ushort* w = (ushort*)((char*)d_ws + off);
    ushort* c_attn_whh = w; w += n_whh;
    ushort* c_proj1    = w; w += n_proj1;
    ushort* c_rnn1_wih = w; w += n_whh;
    ushort* c_rnn1_whh = w; w += n_whh;
    ushort* c_rnn2_wih = w; w += n_whh;
    ushort* c_rnn2_whh = w; w += n_whh;
    ushort* c_proj2    = w; w += n_proj2;
    size_t fixed_bytes = ((size_t)((char*)w - (char*)d_ws) + 255) & ~(size_t)255;

    // per-batch variable cost: ring (T*D fp32) + gi (T*3D bf16)
    const size_t ring_b = (size_t)T_ * D_ * sizeof(float);     // 512000
    const size_t gi_b   = (size_t)T_ * 3 * D_ * sizeof(ushort);// 768000
    size_t avail = (ws_size > fixed_bytes) ? (ws_size - fixed_bytes) : 0;
    int bchunk = (int)(avail / (ring_b + gi_b));
    if (bchunk > B_) bchunk = B_;
    if (bchunk < 1)  bchunk = 1;

    float*  ring = (float*)((char*)d_ws + fixed_bytes);
    ushort* c_gi = (ushort*)((char*)d_ws + fixed_bytes + (size_t)bchunk * ring_b);

    auto pack = [&](const float* src, ushort* dst, int NT, int CH, int dA, int mA, int mB) {
        int n = NT * CH * 8;
        pack_bf16_kernel<<<dim3((n + 255) / 256), dim3(256), 0, stream>>>(
            src, dst, NT, CH, dA, mA, mB);
    };
    pack(attn_whh, c_attn_whh, 1536, 16, 2,   256, 128);
    pack(proj1_w,  c_proj1,    1024, 16, 256, 128, 512);
    pack(rnn1_wih, c_rnn1_wih, 1536, 16, 2,   256, 128);
    pack(rnn1_whh, c_rnn1_whh, 1536, 16, 2,   256, 128);
    pack(rnn2_wih, c_rnn2_wih, 1536, 16, 2,   256, 128);
    pack(rnn2_whh, c_rnn2_whh, 1536, 16, 2,   256, 128);
    pack(proj2_w,  c_proj2,    640,  8,  4,   256, 64);

    for (int b0 = 0; b0 < B_; b0 += bchunk) {
        int nb = (b0 + bchunk <= B_) ? bchunk : (B_ - b0);
        // zero nb step-flags + 1 ticket counter for this chunk
        init_flags_kernel<<<dim3(1), dim3(256), 0, stream>>>(flags, nb + 1);
        prenet_gi_kernel<<<dim3(nb * (T_ / PTT)), dim3(256), 0, stream>>>(
            dec_input, pre_w1, pre_b1, pre_w2, pre_b2, attn_wih, attn_bih,
            c_gi, b0);
        decoder_pipe<<<dim3(2 * nb), dim3(TPB), 0, stream>>>(
            enc_output,
            c_attn_whh, attn_bhh,
            c_proj1, proj1_b,
            c_rnn1_wih, c_rnn1_whh, rnn1_bih, rnn1_bhh,
            c_rnn2_wih, c_rnn2_whh, rnn2_bih, rnn2_bhh,
            c_proj2, proj2_b,
            c_gi, b0, nb,
            flags, ring,
            mel, align);
    }
}

// Round 7
// 16379.787 us; speedup vs baseline: 2.3201x; 2.3201x over previous
//
#include <hip/hip_runtime.h>
#include <cmath>

// Problem dims (fixed by reference)
#define B_   128
#define T_   500
#define MEL_ 80
#define RED_ 2
#define D_   256   // decoder dim
#define E_   128   // encoder/prenet-out dim
#define PRE_ 256   // prenet hidden
#define L_   256   // encoder length
#define TPB  1024
#define ENC_C 256  // ushorts per enc row (512B exactly; XOR-swizzled 16B chunks)
#define PTT  10    // timesteps per pre-pass block (500 % 10 == 0)
#define NSTR 768   // stream-team threads (12 waves); attn team = 4 waves

__device__ __forceinline__ float sigmoidf_(float x) { return 1.f / (1.f + expf(-x)); }
__device__ __forceinline__ float bflo(unsigned u) { return __uint_as_float(u << 16); }
__device__ __forceinline__ float bfhi(unsigned u) { return __uint_as_float(u & 0xFFFF0000u); }
__device__ __forceinline__ float bfval(ushort v) { return __uint_as_float(((unsigned)v) << 16); }
__device__ __forceinline__ ushort f2bf(float f) {
    unsigned u = __float_as_uint(f);
    return (ushort)((u + 0x7FFFu + ((u >> 16) & 1u)) >> 16);
}

// accumulate 8 bf16 (one uint4) against 8 fp32
__device__ __forceinline__ float acc8(uint4 u, const float* vv, float s) {
    s = fmaf(bflo(u.x), vv[0], s);
    s = fmaf(bfhi(u.x), vv[1], s);
    s = fmaf(bflo(u.y), vv[2], s);
    s = fmaf(bfhi(u.y), vv[3], s);
    s = fmaf(bflo(u.z), vv[4], s);
    s = fmaf(bfhi(u.z), vv[5], s);
    s = fmaf(bflo(u.w), vv[6], s);
    s = fmaf(bfhi(u.w), vv[7], s);
    return s;
}

// Wave-group-sequential packed bf16 weights: tasks grouped 64 per wave;
// group g stores all CH chunks contiguously at uint4 index (g*CH + c)*64 + lane.
// Every wave load is 1KB fully contiguous. Works for any thread->task mapping
// as long as a wave's 64 tasks are one aligned contiguous group.
template<int CH>
__device__ __forceinline__ float dotpk(const ushort* __restrict__ wp, int t, const float* v) {
    const uint4* w = reinterpret_cast<const uint4*>(wp) + (t >> 6) * (CH * 64) + (t & 63);
    float s0 = 0.f, s1 = 0.f, s2 = 0.f, s3 = 0.f;
#pragma unroll 2
    for (int c = 0; c < (CH & ~3); c += 4) {
        uint4 u0 = w[(c + 0) * 64];
        uint4 u1 = w[(c + 1) * 64];
        uint4 u2 = w[(c + 2) * 64];
        uint4 u3 = w[(c + 3) * 64];
        s0 = acc8(u0, v + (c + 0) * 8, s0);
        s1 = acc8(u1, v + (c + 1) * 8, s1);
        s2 = acc8(u2, v + (c + 2) * 8, s2);
        s3 = acc8(u3, v + (c + 3) * 8, s3);
    }
    if (CH & 2) {
        constexpr int c0 = CH & ~3;
        uint4 u0 = w[(c0 + 0) * 64];
        uint4 u1 = w[(c0 + 1) * 64];
        s0 = acc8(u0, v + (c0 + 0) * 8, s0);
        s1 = acc8(u1, v + (c0 + 1) * 8, s1);
    }
    return (s0 + s1) + (s2 + s3);
}

// fp32 source -> bf16 wave-group-sequential packed layout
__global__ void pack_bf16_kernel(const float* __restrict__ src,
                                 ushort* __restrict__ dst,
                                 int NT, int CH, int dA, int mA, int mB) {
    int i = blockIdx.x * blockDim.x + threadIdx.x;
    int n = NT * CH * 8;
    if (i >= n) return;
    int i4 = i >> 3, e = i & 7;
    int lane = i4 & 63;
    int q = i4 >> 6;
    int c = q % CH;
    int g = q / CH;
    int t = g * 64 + lane;
    dst[i] = f2bf(src[(t / dA) * mA + (t % dA) * mB + c * 8 + e]);
}

// -------- Pre-pass: prenet + attention-GRU input gates (verified r3/r4) -----
__global__ __launch_bounds__(256) void prenet_gi_kernel(
    const float* __restrict__ dec_input,
    const float* __restrict__ pre_w1, const float* __restrict__ pre_b1,
    const float* __restrict__ pre_w2, const float* __restrict__ pre_b2,
    const float* __restrict__ attn_wih, const float* __restrict__ attn_bih,
    ushort* __restrict__ gi_out,   // chunk-local [nb, T, 3*D] bf16
    int b0)
{
    const int blk = blockIdx.x;
    const int bl  = blk / (T_ / PTT);
    const int b   = b0 + bl;
    const int t0  = (blk % (T_ / PTT)) * PTT;
    const int tid = threadIdx.x;

    __shared__ float fr[PTT][MEL_];
    __shared__ float x1[PTT][PRE_];
    __shared__ float x2[PTT][E_];

    for (int i = tid; i < PTT * MEL_; i += 256) {
        int f = i / MEL_, m = i - f * MEL_;
        fr[f][m] = dec_input[((size_t)b * T_ + t0 + f) * MEL_ + m];
    }
    __syncthreads();

    {
        float acc[PTT];
#pragma unroll
        for (int f = 0; f < PTT; ++f) acc[f] = pre_b1[tid];
        const float4* wr = reinterpret_cast<const float4*>(pre_w1 + tid * MEL_);
        for (int k4 = 0; k4 < MEL_ / 4; ++k4) {
            float4 w = wr[k4];
#pragma unroll
            for (int f = 0; f < PTT; ++f) {
                const float* fp = &fr[f][k4 * 4];
                acc[f] = fmaf(w.x, fp[0], fmaf(w.y, fp[1], fmaf(w.z, fp[2], fmaf(w.w, fp[3], acc[f]))));
            }
        }
#pragma unroll
        for (int f = 0; f < PTT; ++f) x1[f][tid] = fmaxf(acc[f], 0.f);
    }
    __syncthreads();

    if (tid < E_) {
        float acc[PTT];
#pragma unroll
        for (int f = 0; f < PTT; ++f) acc[f] = pre_b2[tid];
        const float4* wr = reinterpret_cast<const float4*>(pre_w2 + tid * PRE_);
        for (int k4 = 0; k4 < PRE_ / 4; ++k4) {
            float4 w = wr[k4];
#pragma unroll
            for (int f = 0; f < PTT; ++f) {
                const float* fp = &x1[f][k4 * 4];
                acc[f] = fmaf(w.x, fp[0], fmaf(w.y, fp[1], fmaf(w.z, fp[2], fmaf(w.w, fp[3], acc[f]))));
            }
        }
#pragma unroll
        for (int f = 0; f < PTT; ++f) x2[f][tid] = fmaxf(acc[f], 0.f);
    }
    __syncthreads();

    for (int r = tid; r < 3 * D_; r += 256) {
        float acc[PTT];
#pragma unroll
        for (int f = 0; f < PTT; ++f) acc[f] = attn_bih[r];
        const float4* wr = reinterpret_cast<const float4*>(attn_wih + r * E_);
        for (int k4 = 0; k4 < E_ / 4; ++k4) {
            float4 w = wr[k4];
#pragma unroll
            for (int f = 0; f < PTT; ++f) {
                const float* fp = &x2[f][k4 * 4];
                acc[f] = fmaf(w.x, fp[0], fmaf(w.y, fp[1], fmaf(w.z, fp[2], fmaf(w.w, fp[3], acc[f]))));
            }
        }
#pragma unroll
        for (int f = 0; f < PTT; ++f)
            gi_out[((size_t)bl * T_ + t0 + f) * (3 * D_) + r] = f2bf(acc[f]);
    }
}

// Persistent decoder with IN-BLOCK wave-role overlap (no cross-block sync):
//  stream team (waves 0..11): attn-gh (signal cntA) -> rnn1/rnn2-gh.
//  attn  team (waves 12..15): wait cntA -> ha update -> scores -> softmax ->
//                             ctx -> ctx combine.  Converge: __syncthreads.
//  Back-end (all 16 waves):   proj1 -> rnn1 -> rnn2 -> proj2.
// LDS spin-flags are workgroup-scope ds-atomics (monotonic, step-tagged);
// all waves of a block are co-resident by definition -> no deadlock possible.
__global__ __launch_bounds__(TPB, 4) void decoder_persist(
    const float* __restrict__ enc_output,  // [B,L,D] fp32
    const ushort* __restrict__ attn_whh, const float* __restrict__ attn_bhh,
    const ushort* __restrict__ proj1_w, const float* __restrict__ proj1_b,
    const ushort* __restrict__ rnn1_wih, const ushort* __restrict__ rnn1_whh,
    const float* __restrict__ rnn1_bih, const float* __restrict__ rnn1_bhh,
    const ushort* __restrict__ rnn2_wih, const ushort* __restrict__ rnn2_whh,
    const float* __restrict__ rnn2_bih, const float* __restrict__ rnn2_bhh,
    const ushort* __restrict__ proj2_w, const float* __restrict__ proj2_b,
    const ushort* __restrict__ gi_g,       // chunk-local [nb,T,3*D] bf16
    int b0,
    float* __restrict__ mel_out,   // [B, T*RED, MEL]
    float* __restrict__ align_out) // [B, L, T]
{
    const int tid  = threadIdx.x;
    const int lane = tid & 63;
    const int bl   = blockIdx.x;
    const int b    = b0 + bl;

    // LDS ~159 KB -> 1 block/CU
    __shared__ __align__(16) ushort s_enc[L_ * ENC_C];   // 131072 B
    __shared__ __align__(16) float P[4608];   // [0,1536): attn-gh then ctx partials
                                              // [1536,3072): rnn1-gh  [3072,4608): rnn2-gh
    __shared__ __align__(16) float Pw[1536];  // wih / proj2 partials (back-end)
    __shared__ __align__(16) float s_ha[D_];
    __shared__ __align__(16) float s_h1[D_];
    __shared__ __align__(16) float s_h2[D_];
    __shared__ __align__(16) float s_dec[D_];
    __shared__ __align__(16) float s_y1[D_];  // doubles as ctx buffer pre-proj1
    __shared__ __align__(16) float s_y2[D_];
    __shared__ __align__(16) float s_al[L_];
    __shared__ float s_pmax[4];
    __shared__ float s_psum[4];
    __shared__ unsigned s_cntA, s_cntB, s_cntS1, s_cntS2, s_cntS3, s_cntC;

    // ---- stage enc[b] fp32 -> bf16 LDS, XOR-swizzled 16B chunks ----
    // chunk c of row r stored at slot (c&24) | ((c&7)^(r&7))
    {
        const float4* eb = reinterpret_cast<const float4*>(enc_output + (size_t)b * L_ * D_);
        for (int i = tid; i < (L_ * D_) / 4; i += TPB) {
            float4 f = eb[i];
            int row = i >> 6;
            int c4  = i & 63;
            int c    = c4 >> 1;
            int half = c4 & 1;
            int slot = (c & 24) | ((c & 7) ^ (row & 7));
            uint2 pk;
            pk.x = (unsigned)f2bf(f.x) | ((unsigned)f2bf(f.y) << 16);
            pk.y = (unsigned)f2bf(f.z) | ((unsigned)f2bf(f.w) << 16);
            *reinterpret_cast<uint2*>(s_enc + row * ENC_C + slot * 8 + half * 4) = pk;
        }
    }
    if (tid < D_) { s_ha[tid] = 0.f; s_h1[tid] = 0.f; s_h2[tid] = 0.f; }
    if (tid == 0) {
        s_cntA = 0u; s_cntB = 0u; s_cntS1 = 0u; s_cntS2 = 0u; s_cntS3 = 0u; s_cntC = 0u;
    }
    __syncthreads();

    // attn-team barrier: each of the 4 waves adds 1 (release), all spin to 4(t+1)
    auto tsync = [&](unsigned* c, unsigned tgt) {
        if (lane == 0)
            __hip_atomic_fetch_add(c, 1u, __ATOMIC_ACQ_REL, __HIP_MEMORY_SCOPE_WORKGROUP);
        while (__hip_atomic_load(c, __ATOMIC_ACQUIRE, __HIP_MEMORY_SCOPE_WORKGROUP) < tgt)
            __builtin_amdgcn_s_sleep(1);
        __builtin_amdgcn_sched_barrier(0);
    };

    for (int t = 0; t < T_; ++t) {
        if (tid < NSTR) {
            // ============ stream team (12 waves) ============
            // [A1] attn gh: 1536 half-dots, 2 per thread (64-aligned groups)
            P[tid] = dotpk<16>(attn_whh, tid, s_ha + (tid & 1) * 128);
            {
                int u = tid + NSTR;
                P[u] = dotpk<16>(attn_whh, u, s_ha + (u & 1) * 128);
            }
            if (lane == 0)
                __hip_atomic_fetch_add(&s_cntA, 1u, __ATOMIC_ACQ_REL, __HIP_MEMORY_SCOPE_WORKGROUP);
            // [A2] rnn gh (prev-step h1/h2; overlaps attn team's front-end)
            for (int u = tid; u < 1536; u += NSTR)
                P[1536 + u] = dotpk<16>(rnn1_whh, u, s_h1 + (u & 1) * 128);
            for (int u = tid; u < 1536; u += NSTR)
                P[3072 + u] = dotpk<16>(rnn2_whh, u, s_h2 + (u & 1) * 128);
        } else {
            // ============ attn team (4 waves, 256 threads) ============
            const int atid = tid - NSTR;       // 0..255 (row / column id)
            const int w    = atid >> 6;        // team-wave 0..3
            const unsigned tgt4 = 4u * (unsigned)(t + 1);
            // prefetch gi + biases while stream team works
            const ushort* gp = gi_g + ((size_t)bl * T_ + t) * (3 * D_);
            ushort g0 = gp[atid], g1 = gp[D_ + atid], g2 = gp[2 * D_ + atid];
            float bhr = attn_bhh[atid], bhz = attn_bhh[D_ + atid], bhn = attn_bhh[2 * D_ + atid];
            // wait for attn-gh (12 stream waves)
            while (__hip_atomic_load(&s_cntA, __ATOMIC_ACQUIRE, __HIP_MEMORY_SCOPE_WORKGROUP)
                   < 12u * (unsigned)(t + 1))
                __builtin_amdgcn_s_sleep(1);
            __builtin_amdgcn_sched_barrier(0);

            // [B] attn GRU combine -> s_ha (row atid)
            {
                float gir = bfval(g0), giz = bfval(g1), gin = bfval(g2);
                float ghr = P[2 * atid] + P[2 * atid + 1] + bhr;
                float ghz = P[2 * (D_ + atid)] + P[2 * (D_ + atid) + 1] + bhz;
                float ghn = P[2 * (2 * D_ + atid)] + P[2 * (2 * D_ + atid) + 1] + bhn;
                float r = sigmoidf_(gir + ghr);
                float z = sigmoidf_(giz + ghz);
                float n = tanhf(gin + r * ghn);
                s_ha[atid] = (1.f - z) * n + z * s_ha[atid];
            }
            tsync(&s_cntB, tgt4);   // all of s_ha visible

            // [C] score row atid: K=256 over swizzled enc (r4 summation order)
            float sc;
            {
                const uint4* rowp = reinterpret_cast<const uint4*>(s_enc + atid * ENC_C);
                int rot = atid & 7;
                float sp[4];
#pragma unroll
                for (int p = 0; p < 4; ++p) {
                    const float* v = s_ha + p * 64;
                    float a0 = 0.f, a1 = 0.f, a2 = 0.f, a3 = 0.f;
#pragma unroll
                    for (int k = 0; k < 8; k += 4) {
                        uint4 u0 = rowp[p * 8 + ((k + 0) ^ rot)];
                        uint4 u1 = rowp[p * 8 + ((k + 1) ^ rot)];
                        uint4 u2 = rowp[p * 8 + ((k + 2) ^ rot)];
                        uint4 u3 = rowp[p * 8 + ((k + 3) ^ rot)];
                        a0 = acc8(u0, v + (k + 0) * 8, a0);
                        a1 = acc8(u1, v + (k + 1) * 8, a1);
                        a2 = acc8(u2, v + (k + 2) * 8, a2);
                        a3 = acc8(u3, v + (k + 3) * 8, a3);
                    }
                    sp[p] = (a0 + a1) + (a2 + a3);
                }
                sc = sp[0] + sp[1] + sp[2] + sp[3];
            }
            // [D] max: wave reduce + cross-wave via s_pmax
            {
                float m = sc;
                for (int o = 32; o > 0; o >>= 1) m = fmaxf(m, __shfl_xor(m, o, 64));
                if (lane == 0) s_pmax[w] = m;
            }
            tsync(&s_cntS1, tgt4);
            float e;
            {
                float mm = fmaxf(fmaxf(s_pmax[0], s_pmax[1]), fmaxf(s_pmax[2], s_pmax[3]));
                e = expf(sc - mm);
                float sm = e;
                for (int o = 32; o > 0; o >>= 1) sm += __shfl_xor(sm, o, 64);
                if (lane == 0) s_psum[w] = sm;
            }
            tsync(&s_cntS2, tgt4);
            {
                float denom = s_psum[0] + s_psum[1] + s_psum[2] + s_psum[3];
                float al = e / denom;
                s_al[atid] = al;
                align_out[((size_t)b * L_ + atid) * T_ + t] = al;
            }
            tsync(&s_cntS3, tgt4);  // all of s_al visible

            // [G] ctx partials: rows w*64..+63, cols cb4*4..+3 (b64 reads,
            // conflict-free across a wave; r4 accumulation order preserved)
            {
                int cb4 = atid & 63;
                int c = cb4 >> 1, half = cb4 & 1;
                const float* alp = s_al + w * 64;
                float ac00 = 0.f, ac01 = 0.f, ac10 = 0.f, ac11 = 0.f;
                float ac20 = 0.f, ac21 = 0.f, ac30 = 0.f, ac31 = 0.f;
#pragma unroll 8
                for (int i = 0; i < 64; ++i) {
                    int r = w * 64 + i;
                    int slot = (c & 24) | ((c & 7) ^ (r & 7));
                    uint2 uv = *reinterpret_cast<const uint2*>(s_enc + r * ENC_C + slot * 8 + half * 4);
                    float a = alp[i];
                    if (i & 1) {
                        ac01 = fmaf(a, bflo(uv.x), ac01);
                        ac11 = fmaf(a, bfhi(uv.x), ac11);
                        ac21 = fmaf(a, bflo(uv.y), ac21);
                        ac31 = fmaf(a, bfhi(uv.y), ac31);
                    } else {
                        ac00 = fmaf(a, bflo(uv.x), ac00);
                        ac10 = fmaf(a, bfhi(uv.x), ac10);
                        ac20 = fmaf(a, bflo(uv.y), ac20);
                        ac30 = fmaf(a, bfhi(uv.y), ac30);
                    }
                }
                int d0 = cb4 * 4;
                P[w * 256 + d0 + 0] = ac00 + ac01;   // reuses attn-gh region (consumed in [B])
                P[w * 256 + d0 + 1] = ac10 + ac11;
                P[w * 256 + d0 + 2] = ac20 + ac21;
                P[w * 256 + d0 + 3] = ac30 + ac31;
            }
            tsync(&s_cntC, tgt4);
            // [H] ctx combine -> s_y1 (free until rnn1 combine)
            s_y1[atid] = P[atid] + P[256 + atid] + P[512 + atid] + P[768 + atid];
        }
        __syncthreads();   // converge: gh in P[1536..4608), ctx in s_y1, ha ready

        // ============ back-end: full block ============
        // [I] proj1 partials: 1024 tasks; cat = [ctx(s_y1), ha]
        {
            int p = tid >> 8;
            const float* v = (p < 2) ? (s_y1 + p * 128) : (s_ha + (p - 2) * 128);
            P[tid] = dotpk<16>(proj1_w, tid, v);   // P[0..1024): free (ctx consumed)
        }
        __syncthreads();
        // [J] proj1 combine
        if (tid < D_)
            s_dec[tid] = P[tid] + P[256 + tid] + P[512 + tid] + P[768 + tid] + proj1_b[tid];
        __syncthreads();

        // [K] rnn1 wih partials
        for (int task = tid; task < 1536; task += TPB)
            Pw[task] = dotpk<16>(rnn1_wih, task, s_dec + (task & 1) * 128);
        __syncthreads();
        // rnn1 combine (gh from P[1536..3072))
        if (tid < D_) {
            float gir = Pw[2 * tid] + Pw[2 * tid + 1] + rnn1_bih[tid];
            float giz = Pw[2 * (D_ + tid)] + Pw[2 * (D_ + tid) + 1] + rnn1_bih[D_ + tid];
            float gin = Pw[2 * (2 * D_ + tid)] + Pw[2 * (2 * D_ + tid) + 1] + rnn1_bih[2 * D_ + tid];
            const float* gh = P + 1536;
            float ghr = gh[2 * tid] + gh[2 * tid + 1] + rnn1_bhh[tid];
            float ghz = gh[2 * (D_ + tid)] + gh[2 * (D_ + tid) + 1] + rnn1_bhh[D_ + tid];
            float ghn = gh[2 * (2 * D_ + tid)] + gh[2 * (2 * D_ + tid) + 1] + rnn1_bhh[2 * D_ + tid];
            float r = sigmoidf_(gir + ghr);
            float z = sigmoidf_(giz + ghz);
            float n = tanhf(gin + r * ghn);
            float hn = (1.f - z) * n + z * s_h1[tid];
            s_h1[tid] = hn;
            s_y1[tid] = s_dec[tid] + hn;
        }
        __syncthreads();

        // [L] rnn2 wih partials
        for (int task = tid; task < 1536; task += TPB)
            Pw[task] = dotpk<16>(rnn2_wih, task, s_y1 + (task & 1) * 128);
        __syncthreads();
        // rnn2 combine (gh from P[3072..4608))
        if (tid < D_) {
            float gir = Pw[2 * tid] + Pw[2 * tid + 1] + rnn2_bih[tid];
            float giz = Pw[2 * (D_ + tid)] + Pw[2 * (D_ + tid) + 1] + rnn2_bih[D_ + tid];
            float gin = Pw[2 * (2 * D_ + tid)] + Pw[2 * (2 * D_ + tid) + 1] + rnn2_bih[2 * D_ + tid];
            const float* gh = P + 3072;
            float ghr = gh[2 * tid] + gh[2 * tid + 1] + rnn2_bhh[tid];
            float ghz = gh[2 * (D_ + tid)] + gh[2 * (D_ + tid) + 1] + rnn2_bhh[D_ + tid];
            float ghn = gh[2 * (2 * D_ + tid)] + gh[2 * (2 * D_ + tid) + 1] + rnn2_bhh[2 * D_ + tid];
            float r = sigmoidf_(gir + ghr);
            float z = sigmoidf_(giz + ghz);
            float n = tanhf(gin + r * ghn);
            float hn = (1.f - z) * n + z * s_h2[tid];
            s_h2[tid] = hn;
            s_y2[tid] = s_y1[tid] + hn;
        }
        __syncthreads();

        // [M] proj2 partials: 640 tasks
        if (tid < 640)
            Pw[tid] = dotpk<8>(proj2_w, tid, s_y2 + (tid & 3) * 64);
        __syncthreads();
        // [N] proj2 combine + mel store. No trailing barrier: next phase writes
        // P (disjoint from Pw); Pw next written at [K] after 3 barriers.
        if (tid < MEL_ * RED_) {
            float s = Pw[4 * tid] + Pw[4 * tid + 1] + Pw[4 * tid + 2] + Pw[4 * tid + 3] + proj2_b[tid];
            mel_out[(size_t)b * (T_ * RED_ * MEL_) + (size_t)t * (MEL_ * RED_) + tid] = s;
        }
    }
}

extern "C" void kernel_launch(void* const* d_in, const int* in_sizes, int n_in,
                              void* d_out, int out_size, void* d_ws, size_t ws_size,
                              hipStream_t stream) {
    const float* dec_input = (const float*)d_in[0];
    const float* enc_output= (const float*)d_in[1];
    const float* pre_w1    = (const float*)d_in[2];
    const float* pre_b1    = (const float*)d_in[3];
    const float* pre_w2    = (const float*)d_in[4];
    const float* pre_b2    = (const float*)d_in[5];
    const float* attn_wih  = (const float*)d_in[6];
    const float* attn_whh  = (const float*)d_in[7];
    const float* attn_bih  = (const float*)d_in[8];
    const float* attn_bhh  = (const float*)d_in[9];
    const float* proj1_w   = (const float*)d_in[10];
    const float* proj1_b   = (const float*)d_in[11];
    const float* rnn1_wih  = (const float*)d_in[12];
    const float* rnn1_whh  = (const float*)d_in[13];
    const float* rnn1_bih  = (const float*)d_in[14];
    const float* rnn1_bhh  = (const float*)d_in[15];
    const float* rnn2_wih  = (const float*)d_in[16];
    const float* rnn2_whh  = (const float*)d_in[17];
    const float* rnn2_bih  = (const float*)d_in[18];
    const float* rnn2_bhh  = (const float*)d_in[19];
    const float* proj2_w   = (const float*)d_in[20];
    const float* proj2_b   = (const float*)d_in[21];

    float* mel   = (float*)d_out;
    float* align = (float*)d_out + (size_t)B_ * T_ * RED_ * MEL_;

    // bf16 packed weight scratch
    const int n_whh   = 3 * D_ * D_;        // 196608
    const int n_proj1 = D_ * 2 * D_;        // 131072
    const int n_proj2 = MEL_ * RED_ * D_;   // 40960

    ushort* w = (ushort*)d_ws;
    ushort* c_attn_whh = w; w += n_whh;
    ushort* c_proj1    = w; w += n_proj1;
    ushort* c_rnn1_wih = w; w += n_whh;
    ushort* c_rnn1_whh = w; w += n_whh;
    ushort* c_rnn2_wih = w; w += n_whh;
    ushort* c_rnn2_whh = w; w += n_whh;
    ushort* c_proj2    = w; w += n_proj2;
    ushort* c_gi       = w;   // gi chunk buffer starts here

    auto pack = [&](const float* src, ushort* dst, int NT, int CH, int dA, int mA, int mB) {
        int n = NT * CH * 8;
        pack_bf16_kernel<<<dim3((n + 255) / 256), dim3(256), 0, stream>>>(
            src, dst, NT, CH, dA, mA, mB);
    };
    pack(attn_whh, c_attn_whh, 1536, 16, 2,   256, 128);  // row=t>>1, half=t&1
    pack(proj1_w,  c_proj1,    1024, 16, 256, 128, 512);  // row=t&255, p=t>>8
    pack(rnn1_wih, c_rnn1_wih, 1536, 16, 2,   256, 128);
    pack(rnn1_whh, c_rnn1_whh, 1536, 16, 2,   256, 128);
    pack(rnn2_wih, c_rnn2_wih, 1536, 16, 2,   256, 128);
    pack(rnn2_whh, c_rnn2_whh, 1536, 16, 2,   256, 128);
    pack(proj2_w,  c_proj2,    640,  8,  4,   256, 64);   // row=t>>2, p=t&3

    // gi chunking by available workspace (observed harness ws fits all 128)
    const size_t gi_per_b = (size_t)T_ * 3 * D_;          // elems per batch
    size_t used = (size_t)((char*)c_gi - (char*)d_ws);
    size_t avail = (ws_size > used) ? (ws_size - used) : 0;
    int bchunk = (int)(avail / (gi_per_b * sizeof(ushort)));
    if (bchunk > B_) bchunk = B_;
    if (bchunk < 1)  bchunk = 1;

    for (int b0 = 0; b0 < B_; b0 += bchunk) {
        int nb = (b0 + bchunk <= B_) ? bchunk : (B_ - b0);
        prenet_gi_kernel<<<dim3(nb * (T_ / PTT)), dim3(256), 0, stream>>>(
            dec_input, pre_w1, pre_b1, pre_w2, pre_b2, attn_wih, attn_bih,
            c_gi, b0);
        decoder_persist<<<dim3(nb), dim3(TPB), 0, stream>>>(
            enc_output,
            c_attn_whh, attn_bhh,
            c_proj1, proj1_b,
            c_rnn1_wih, c_rnn1_whh, rnn1_bih, rnn1_bhh,
            c_rnn2_wih, c_rnn2_whh, rnn2_bih, rnn2_bhh,
            c_proj2, proj2_b,
            c_gi, b0,
            mel, align);
    }
}